// Round 6
// baseline (801.724 us; speedup 1.0000x reference)
//
#include <hip/hip_runtime.h>
#include <stdint.h>

typedef unsigned short u16;
typedef __bf16 bf16x8 __attribute__((ext_vector_type(8)));
typedef float f32x4 __attribute__((ext_vector_type(4)));

#define AS1 __attribute__((address_space(1)))
#define AS3 __attribute__((address_space(3)))

__device__ __forceinline__ void g2l16(const void* g, void* l) {
  __builtin_amdgcn_global_load_lds((AS1 void*)(void*)g, (AS3 void*)l, 16, 0, 0);
}

__device__ __forceinline__ u16 f2bf(float f) {
  union { float f; uint32_t u; } v; v.f = f;
  return (u16)((v.u + 0x7fffu + ((v.u >> 16) & 1u)) >> 16);
}
__device__ __forceinline__ float bf2f(u16 b) {
  union { uint32_t u; float f; } v; v.u = ((uint32_t)b) << 16;
  return v.f;
}

// ---- merged prologue: fp32->bf16 casts (x,Wg,Wu,Wd) + top2 + LoRA panels ----
// blocks [0, 49408): cast region, 12648448 float4s
// blocks [49408, 60736): prep region, 2899968 threads:
//   AxT 524288 | AdT 704512 | BgT 704512 | BuT 704512 | BdT 262144
__global__ void k_pre(const float* __restrict__ x, u16* __restrict__ xb,
                      const float* __restrict__ Wg, u16* __restrict__ Wgb,
                      const float* __restrict__ Wu, u16* __restrict__ Wub,
                      const float* __restrict__ Wd, u16* __restrict__ Wdb,
                      const float* __restrict__ gv,
                      const float* __restrict__ Ag, const float* __restrict__ Au,
                      const float* __restrict__ Ad,
                      const float* __restrict__ Bg, const float* __restrict__ Bu,
                      const float* __restrict__ Bd,
                      u16* __restrict__ AxT, u16* __restrict__ AdT,
                      u16* __restrict__ BgT, u16* __restrict__ BuT,
                      u16* __restrict__ BdT) {
  __shared__ int sidx[8];
  if (blockIdx.x < 49408) {
    int i = blockIdx.x * 256 + threadIdx.x;
    const float* in; u16* out; int j;
    if (i < 4194304) { in = x; out = xb; j = i; }
    else if (i < 4194304 + 2818048) { in = Wg; out = Wgb; j = i - 4194304; }
    else if (i < 4194304 + 2 * 2818048) { in = Wu; out = Wub; j = i - 4194304 - 2818048; }
    else { in = Wd; out = Wdb; j = i - 4194304 - 2 * 2818048; }
    float4 v = ((const float4*)in)[j];
    ushort4 o = make_ushort4(f2bf(v.x), f2bf(v.y), f2bf(v.z), f2bf(v.w));
    ((ushort4*)out)[j] = o;
    return;
  }
  if (threadIdx.x == 0) {
    #pragma unroll
    for (int b = 0; b < 4; ++b) {
      const float* g = gv + b * 8;
      int i1 = 0; float v1 = g[0];
      for (int e = 1; e < 8; ++e) if (g[e] > v1) { v1 = g[e]; i1 = e; }
      int i2 = -1; float v2 = -3.0e38f;
      for (int e = 0; e < 8; ++e) if (e != i1 && g[e] > v2) { v2 = g[e]; i2 = e; }
      sidx[2 * b] = i1; sidx[2 * b + 1] = i2;
    }
  }
  __syncthreads();
  int t = (blockIdx.x - 49408) * 256 + threadIdx.x;
  if (t < 524288) {  // AxT: Kd=2048, jmax=64 (gate|up stacked)
    int h = t % 2048;
    int j = (t / 2048) & 63;
    int b = t / (2048 * 64);
    const float* src = (j >= 32) ? Au : Ag;
    int jj = j & 31;
    int e = sidx[2 * b + ((jj >> 4) & 1)];
    AxT[t] = f2bf(src[((size_t)e * 2048 + h) * 16 + (jj & 15)]);
    return;
  }
  t -= 524288;
  if (t < 704512) {  // AdT: Kd=5504, jmax=32
    int h = t % 5504;
    int j = (t / 5504) & 31;
    int b = t / (5504 * 32);
    int e = sidx[2 * b + ((j >> 4) & 1)];
    AdT[t] = f2bf(Ad[((size_t)e * 5504 + h) * 16 + (j & 15)]);
    return;
  }
  t -= 704512;
  if (t < 704512) {  // BgT: N=5504
    int j = t & 31;
    int n = (t >> 5) % 5504;
    int b = t / (5504 * 32);
    int e = (j & 16) ? sidx[2 * b + 1] : sidx[2 * b];
    BgT[t] = f2bf(Bg[((size_t)e * 16 + (j & 15)) * 5504 + n]);
    return;
  }
  t -= 704512;
  if (t < 704512) {  // BuT: N=5504
    int j = t & 31;
    int n = (t >> 5) % 5504;
    int b = t / (5504 * 32);
    int e = (j & 16) ? sidx[2 * b + 1] : sidx[2 * b];
    BuT[t] = f2bf(Bu[((size_t)e * 16 + (j & 15)) * 5504 + n]);
    return;
  }
  t -= 704512;
  if (t < 262144) {  // BdT: N=2048
    int j = t & 31;
    int n = (t >> 5) % 2048;
    int b = t / (2048 * 32);
    int e = (j & 16) ? sidx[2 * b + 1] : sidx[2 * b];
    BdT[t] = f2bf(Bd[((size_t)e * 16 + (j & 15)) * 2048 + n]);
  }
}

// ---- skinny MFMA GEMM with split-K ----
template <int N2>
__global__ __launch_bounds__(256) void k_skinny(
    const u16* __restrict__ A, const u16* __restrict__ BT,
    float* __restrict__ part, int M, int K, int total_iters, int iters_per_chunk) {
  __shared__ u16 sA[128 * 64];
  __shared__ u16 sB[N2 * 64];
  int nm = M >> 7;
  int bm = blockIdx.x % nm, chunk = blockIdx.x / nm;
  int m0 = bm << 7;
  int batch = m0 >> 11;
  int tid = threadIdx.x, lane = tid & 63, w = tid >> 6;
  int kb = chunk * iters_per_chunk;
  int ke = min(total_iters, kb + iters_per_chunk);

  const u16* Bb = BT + (size_t)batch * N2 * K;

  const u16* ga[4]; u16* la[4];
  #pragma unroll
  for (int t = 0; t < 4; ++t) {
    int cb = 4 * w + t;
    int q = cb * 64 + lane;
    int row = q >> 3;
    int c = (q & 7) ^ (row & 7);
    ga[t] = A + (size_t)(m0 + row) * K + (size_t)kb * 64 + c * 8;
    la[t] = sA + cb * 512;
  }
  constexpr int nB = N2 / 32;
  const u16* gb[nB]; u16* lb[nB];
  #pragma unroll
  for (int t = 0; t < nB; ++t) {
    int cb = nB * w + t;
    int q = cb * 64 + lane;
    int row = q >> 3;
    int c = (q & 7) ^ (row & 7);
    gb[t] = Bb + (size_t)row * K + (size_t)kb * 64 + c * 8;
    lb[t] = sB + cb * 512;
  }

  f32x4 acc[2][N2 / 16] = {};
  for (int kt = kb; kt < ke; ++kt) {
    #pragma unroll
    for (int t = 0; t < 4; ++t) { g2l16(ga[t], la[t]); ga[t] += 64; }
    #pragma unroll
    for (int t = 0; t < nB; ++t) { g2l16(gb[t], lb[t]); gb[t] += 64; }
    __syncthreads();
    #pragma unroll
    for (int ks = 0; ks < 2; ++ks) {
      int cb0 = ks * 4 + (lane >> 4);
      bf16x8 af[2], bfr[N2 / 16];
      #pragma unroll
      for (int mi = 0; mi < 2; ++mi) {
        int row = 32 * w + mi * 16 + (lane & 15);
        af[mi] = *(const bf16x8*)(sA + (row * 8 + (cb0 ^ (row & 7))) * 8);
      }
      #pragma unroll
      for (int ni = 0; ni < N2 / 16; ++ni) {
        int row = ni * 16 + (lane & 15);
        bfr[ni] = *(const bf16x8*)(sB + (row * 8 + (cb0 ^ (row & 7))) * 8);
      }
      #pragma unroll
      for (int mi = 0; mi < 2; ++mi)
        #pragma unroll
        for (int ni = 0; ni < N2 / 16; ++ni)
          acc[mi][ni] = __builtin_amdgcn_mfma_f32_16x16x32_bf16(
              af[mi], bfr[ni], acc[mi][ni], 0, 0, 0);
    }
    __syncthreads();
  }

  int rb = (lane >> 4) * 4, cc = lane & 15;
  #pragma unroll
  for (int mi = 0; mi < 2; ++mi)
    #pragma unroll
    for (int ni = 0; ni < N2 / 16; ++ni)
      #pragma unroll
      for (int reg = 0; reg < 4; ++reg) {
        int gr = m0 + 32 * w + mi * 16 + rb + reg;
        int gc = ni * 16 + cc;
        part[((size_t)chunk * M + gr) * N2 + gc] = acc[mi][ni][reg];
      }
}

// ---- finalize split-K: out = bf16(2 * sum_chunks part) ----
__global__ void k_fin(const float* __restrict__ part, u16* __restrict__ out0,
                      u16* __restrict__ out1, int M, int N2, int nch) {
  int t = blockIdx.x * 256 + threadIdx.x;
  if (t >= M * N2) return;
  float s = 0.f;
  for (int c = 0; c < nch; ++c) s += part[(size_t)c * M * N2 + t];
  int j = t % N2, bs = t / N2;
  u16 v = f2bf(2.0f * s);
  if (N2 == 64) {
    if (j < 32) out0[(size_t)bs * 32 + j] = v;
    else        out1[(size_t)bs * 32 + (j - 32)] = v;
  } else {
    out0[(size_t)bs * 32 + j] = v;
  }
}

// ================= fused gate+up GEMM =================
// One block computes BOTH gate and up 128x128 output tiles for (m0,n0):
// A (xb) staged ONCE per K-tile, Wg-tile and Wu-tile staged alongside;
// 32 MFMA per ks (16 gate + 16 up) against one A-fragment load. Epilogue
// h = silu(g)*u written directly (no gbuf round-trip, one fewer bf16 round).
__global__ __launch_bounds__(256, 2)
void k_gemmGU(const u16* __restrict__ A, const u16* __restrict__ Bg_,
              const u16* __restrict__ Bu_,
              const u16* __restrict__ A2g, const u16* __restrict__ A2u,
              const u16* __restrict__ B2g, const u16* __restrict__ B2u,
              u16* __restrict__ Out, int N, int K) {
  __shared__ u16 sA[128 * 64];
  __shared__ u16 sG[128 * 64];
  __shared__ u16 sU[128 * 64];
  int nt = N >> 7;
  int nm = gridDim.x / nt;
  int perx = nm >> 3;
  int xcd = blockIdx.x & 7;
  int v = blockIdx.x >> 3;
  int bn = v / perx;
  int bm = xcd * perx + (v - bn * perx);
  int m0 = bm << 7, n0 = bn << 7;
  int batch = m0 >> 11;
  int tid = threadIdx.x, lane = tid & 63, w = tid >> 6;
  int mo = (w & 1) << 6, no = (w >> 1) << 6;

  const u16* ga[4]; const u16* gg[4]; const u16* gu[4];
  u16* la[4]; u16* lg[4]; u16* lu[4];
  #pragma unroll
  for (int t = 0; t < 4; ++t) {
    int cb = 4 * w + t;
    int q = cb * 64 + lane;
    int row = q >> 3;
    int c = (q & 7) ^ (row & 7);
    ga[t] = A + (size_t)(m0 + row) * K + c * 8;
    gg[t] = Bg_ + (size_t)(n0 + row) * K + c * 8;
    gu[t] = Bu_ + (size_t)(n0 + row) * K + c * 8;
    la[t] = sA + cb * 512;
    lg[t] = sG + cb * 512;
    lu[t] = sU + cb * 512;
  }

  f32x4 accg[4][4] = {};
  f32x4 accu[4][4] = {};

  int kiters = K >> 6;
  for (int kt = 0; kt < kiters; ++kt) {
    #pragma unroll
    for (int t = 0; t < 4; ++t) { g2l16(ga[t], la[t]); ga[t] += 64; }
    #pragma unroll
    for (int t = 0; t < 4; ++t) { g2l16(gg[t], lg[t]); gg[t] += 64; }
    #pragma unroll
    for (int t = 0; t < 4; ++t) { g2l16(gu[t], lu[t]); gu[t] += 64; }
    __syncthreads();
    #pragma unroll
    for (int ks = 0; ks < 2; ++ks) {
      bf16x8 af[4], bgf[4], buf_[4];
      int cb0 = ks * 4 + (lane >> 4);
      #pragma unroll
      for (int mi = 0; mi < 4; ++mi) {
        int row = mo + mi * 16 + (lane & 15);
        af[mi] = *(const bf16x8*)(sA + (row * 8 + (cb0 ^ (row & 7))) * 8);
      }
      #pragma unroll
      for (int ni = 0; ni < 4; ++ni) {
        int row = no + ni * 16 + (lane & 15);
        bgf[ni] = *(const bf16x8*)(sG + (row * 8 + (cb0 ^ (row & 7))) * 8);
        buf_[ni] = *(const bf16x8*)(sU + (row * 8 + (cb0 ^ (row & 7))) * 8);
      }
      #pragma unroll
      for (int mi = 0; mi < 4; ++mi)
        #pragma unroll
        for (int ni = 0; ni < 4; ++ni) {
          accg[mi][ni] = __builtin_amdgcn_mfma_f32_16x16x32_bf16(
              af[mi], bgf[ni], accg[mi][ni], 0, 0, 0);
          accu[mi][ni] = __builtin_amdgcn_mfma_f32_16x16x32_bf16(
              af[mi], buf_[ni], accu[mi][ni], 0, 0, 0);
        }
    }
    __syncthreads();
  }

  // LoRA extra K=32 step: gate uses (A2g,B2g), up uses (A2u,B2u)
  {
    const u16* B2gb = B2g + (size_t)batch * N * 32;
    const u16* B2ub = B2u + (size_t)batch * N * 32;
    #pragma unroll
    for (int t = 0; t < 2; ++t) {
      int cb = 2 * w + t;
      int q = cb * 64 + lane;
      int row = q >> 2;
      int c = (q & 3) ^ (row & 3);
      g2l16(A2g + (size_t)(m0 + row) * 32 + c * 8, sA + cb * 512);
      g2l16(A2u + (size_t)(m0 + row) * 32 + c * 8, sA + 4096 + cb * 512);
      g2l16(B2gb + (size_t)(n0 + row) * 32 + c * 8, sG + cb * 512);
      g2l16(B2ub + (size_t)(n0 + row) * 32 + c * 8, sU + cb * 512);
    }
    __syncthreads();
    int c0 = lane >> 4;
    bf16x8 ag2[4], au2[4], bg2[4], bu2[4];
    #pragma unroll
    for (int mi = 0; mi < 4; ++mi) {
      int row = mo + mi * 16 + (lane & 15);
      ag2[mi] = *(const bf16x8*)(sA + (row * 4 + (c0 ^ (row & 3))) * 8);
      au2[mi] = *(const bf16x8*)(sA + 4096 + (row * 4 + (c0 ^ (row & 3))) * 8);
    }
    #pragma unroll
    for (int ni = 0; ni < 4; ++ni) {
      int row = no + ni * 16 + (lane & 15);
      bg2[ni] = *(const bf16x8*)(sG + (row * 4 + (c0 ^ (row & 3))) * 8);
      bu2[ni] = *(const bf16x8*)(sU + (row * 4 + (c0 ^ (row & 3))) * 8);
    }
    #pragma unroll
    for (int mi = 0; mi < 4; ++mi)
      #pragma unroll
      for (int ni = 0; ni < 4; ++ni) {
        accg[mi][ni] = __builtin_amdgcn_mfma_f32_16x16x32_bf16(
            ag2[mi], bg2[ni], accg[mi][ni], 0, 0, 0);
        accu[mi][ni] = __builtin_amdgcn_mfma_f32_16x16x32_bf16(
            au2[mi], bu2[ni], accu[mi][ni], 0, 0, 0);
      }
  }

  // epilogue: h = silu(g) * u, bf16
  int rb = (lane >> 4) * 4;
  int cc = lane & 15;
  #pragma unroll
  for (int mi = 0; mi < 4; ++mi) {
    #pragma unroll
    for (int ni = 0; ni < 4; ++ni) {
      #pragma unroll
      for (int reg = 0; reg < 4; ++reg) {
        int gr = m0 + mo + mi * 16 + rb + reg;
        int gc = n0 + no + ni * 16 + cc;
        size_t pos = (size_t)gr * N + gc;
        float gvv = accg[mi][ni][reg];
        float uvv = accu[mi][ni][reg];
        gvv = gvv / (1.f + __expf(-gvv));
        Out[pos] = f2bf(gvv * uvv);
      }
    }
  }
}

// ================= dual-m-tile down GEMM =================
// One block computes out tiles (m0, n0) and (m0+128, n0): Wd-tile staged ONCE,
// 32 MFMA per wave per K-step (same proven profile as k_gemmGU).
__global__ __launch_bounds__(256, 2)
void k_gemmD(const u16* __restrict__ A, const u16* __restrict__ Bm,
             const u16* __restrict__ A2, const u16* __restrict__ B2,
             float* __restrict__ Out, int N, int K) {
  __shared__ u16 sA0[128 * 64];
  __shared__ u16 sA1[128 * 64];
  __shared__ u16 sB[128 * 64];
  int nt = N >> 7;                  // 16
  int nm = gridDim.x / nt;          // 32 m-pairs
  int perx = nm >> 3;
  int xcd = blockIdx.x & 7;
  int v = blockIdx.x >> 3;
  int bn = v / perx;
  int bm = xcd * perx + (v - bn * perx);
  int m0 = bm << 8, n0 = bn << 7;
  int batch = m0 >> 11;             // 256-block never straddles a batch
  int tid = threadIdx.x, lane = tid & 63, w = tid >> 6;
  int mo = (w & 1) << 6, no = (w >> 1) << 6;

  const u16* ga0[4]; const u16* ga1[4]; const u16* gb[4];
  u16* la0[4]; u16* la1[4]; u16* lb[4];
  #pragma unroll
  for (int t = 0; t < 4; ++t) {
    int cb = 4 * w + t;
    int q = cb * 64 + lane;
    int row = q >> 3;
    int c = (q & 7) ^ (row & 7);
    ga0[t] = A + (size_t)(m0 + row) * K + c * 8;
    ga1[t] = A + (size_t)(m0 + 128 + row) * K + c * 8;
    gb[t]  = Bm + (size_t)(n0 + row) * K + c * 8;
    la0[t] = sA0 + cb * 512;
    la1[t] = sA1 + cb * 512;
    lb[t]  = sB + cb * 512;
  }

  f32x4 acc0[4][4] = {};
  f32x4 acc1[4][4] = {};

  int kiters = K >> 6;
  for (int kt = 0; kt < kiters; ++kt) {
    #pragma unroll
    for (int t = 0; t < 4; ++t) { g2l16(ga0[t], la0[t]); ga0[t] += 64; }
    #pragma unroll
    for (int t = 0; t < 4; ++t) { g2l16(ga1[t], la1[t]); ga1[t] += 64; }
    #pragma unroll
    for (int t = 0; t < 4; ++t) { g2l16(gb[t], lb[t]); gb[t] += 64; }
    __syncthreads();
    #pragma unroll
    for (int ks = 0; ks < 2; ++ks) {
      bf16x8 af0[4], af1[4], bfr[4];
      int cb0 = ks * 4 + (lane >> 4);
      #pragma unroll
      for (int mi = 0; mi < 4; ++mi) {
        int row = mo + mi * 16 + (lane & 15);
        af0[mi] = *(const bf16x8*)(sA0 + (row * 8 + (cb0 ^ (row & 7))) * 8);
        af1[mi] = *(const bf16x8*)(sA1 + (row * 8 + (cb0 ^ (row & 7))) * 8);
      }
      #pragma unroll
      for (int ni = 0; ni < 4; ++ni) {
        int row = no + ni * 16 + (lane & 15);
        bfr[ni] = *(const bf16x8*)(sB + (row * 8 + (cb0 ^ (row & 7))) * 8);
      }
      #pragma unroll
      for (int mi = 0; mi < 4; ++mi)
        #pragma unroll
        for (int ni = 0; ni < 4; ++ni) {
          acc0[mi][ni] = __builtin_amdgcn_mfma_f32_16x16x32_bf16(
              af0[mi], bfr[ni], acc0[mi][ni], 0, 0, 0);
          acc1[mi][ni] = __builtin_amdgcn_mfma_f32_16x16x32_bf16(
              af1[mi], bfr[ni], acc1[mi][ni], 0, 0, 0);
        }
    }
    __syncthreads();
  }

  // LoRA extra K=32 step: ha tiles at m0 and m0+128, BdT shared
  {
    const u16* B2b = B2 + (size_t)batch * N * 32;
    #pragma unroll
    for (int t = 0; t < 2; ++t) {
      int cb = 2 * w + t;
      int q = cb * 64 + lane;
      int row = q >> 2;
      int c = (q & 3) ^ (row & 3);
      g2l16(A2 + (size_t)(m0 + row) * 32 + c * 8, sA0 + cb * 512);
      g2l16(A2 + (size_t)(m0 + 128 + row) * 32 + c * 8, sA1 + cb * 512);
      g2l16(B2b + (size_t)(n0 + row) * 32 + c * 8, sB + cb * 512);
    }
    __syncthreads();
    int c0 = lane >> 4;
    bf16x8 af0[4], af1[4], bfr[4];
    #pragma unroll
    for (int mi = 0; mi < 4; ++mi) {
      int row = mo + mi * 16 + (lane & 15);
      af0[mi] = *(const bf16x8*)(sA0 + (row * 4 + (c0 ^ (row & 3))) * 8);
      af1[mi] = *(const bf16x8*)(sA1 + (row * 4 + (c0 ^ (row & 3))) * 8);
    }
    #pragma unroll
    for (int ni = 0; ni < 4; ++ni) {
      int row = no + ni * 16 + (lane & 15);
      bfr[ni] = *(const bf16x8*)(sB + (row * 4 + (c0 ^ (row & 3))) * 8);
    }
    #pragma unroll
    for (int mi = 0; mi < 4; ++mi)
      #pragma unroll
      for (int ni = 0; ni < 4; ++ni) {
        acc0[mi][ni] = __builtin_amdgcn_mfma_f32_16x16x32_bf16(
            af0[mi], bfr[ni], acc0[mi][ni], 0, 0, 0);
        acc1[mi][ni] = __builtin_amdgcn_mfma_f32_16x16x32_bf16(
            af1[mi], bfr[ni], acc1[mi][ni], 0, 0, 0);
      }
  }

  int rb = (lane >> 4) * 4;
  int cc = lane & 15;
  #pragma unroll
  for (int mi = 0; mi < 4; ++mi) {
    #pragma unroll
    for (int ni = 0; ni < 4; ++ni) {
      #pragma unroll
      for (int reg = 0; reg < 4; ++reg) {
        int gr = m0 + mo + mi * 16 + rb + reg;
        int gc = n0 + no + ni * 16 + cc;
        Out[(size_t)gr * N + gc] = acc0[mi][ni][reg];
        Out[(size_t)(gr + 128) * N + gc] = acc1[mi][ni][reg];
      }
    }
  }
}

extern "C" void kernel_launch(void* const* d_in, const int* in_sizes, int n_in,
                              void* d_out, int out_size, void* d_ws, size_t ws_size,
                              hipStream_t stream) {
  const float* x  = (const float*)d_in[0];
  const float* gv = (const float*)d_in[1];
  const float* Wg = (const float*)d_in[2];
  const float* Ag = (const float*)d_in[3];
  const float* Bg = (const float*)d_in[4];
  const float* Wu = (const float*)d_in[5];
  const float* Au = (const float*)d_in[6];
  const float* Bu = (const float*)d_in[7];
  const float* Wd = (const float*)d_in[8];
  const float* Ad = (const float*)d_in[9];
  const float* Bd = (const float*)d_in[10];
  float* out = (float*)d_out;

  char* ws = (char*)d_ws;
  size_t off = 0;
  auto alloc = [&](size_t bytes) -> void* {
    void* p = ws + off;
    off = (off + bytes + 255) & ~(size_t)255;
    return p;
  };
  u16* xb   = (u16*)alloc((size_t)8192 * 2048 * 2);
  u16* Wgb  = (u16*)alloc((size_t)5504 * 2048 * 2);
  u16* Wub  = (u16*)alloc((size_t)5504 * 2048 * 2);
  u16* Wdb  = (u16*)alloc((size_t)2048 * 5504 * 2);
  u16* xag  = (u16*)alloc((size_t)8192 * 32 * 2);
  u16* xau  = (u16*)alloc((size_t)8192 * 32 * 2);
  u16* ha   = (u16*)alloc((size_t)8192 * 32 * 2);
  u16* BgT  = (u16*)alloc((size_t)4 * 5504 * 32 * 2);
  u16* BuT  = (u16*)alloc((size_t)4 * 5504 * 32 * 2);
  u16* BdT  = (u16*)alloc((size_t)4 * 2048 * 32 * 2);
  u16* AxT  = (u16*)alloc((size_t)4 * 64 * 2048 * 2);
  u16* AdT  = (u16*)alloc((size_t)4 * 32 * 5504 * 2);
  u16* gbuf = (u16*)alloc((size_t)8192 * 5504 * 2);
  if (off > ws_size) return;

  // split-K=16 partial buffers live in dead regions:
  float* part_xa = (float*)gbuf;   // 16*8192*64*4 = 33.5MB <= 90MB, dead until GU
  float* part_ha = (float*)Wgb;    // 16*8192*32*4 = 16.8MB <= 22.5MB, dead after GU

  // merged casts + LoRA prep: 49408 cast blocks + 11328 prep blocks
  k_pre<<<60736, 256, 0, stream>>>(x, xb, Wg, Wgb, Wu, Wub, Wd, Wdb,
                                   gv, Ag, Au, Ad, Bg, Bu, Bd,
                                   AxT, AdT, BgT, BuT, BdT);

  // xa: [8192 x 64] = xb @ AxT^T, split-K 16 chunks (K=2048)
  k_skinny<64><<<64 * 16, 256, 0, stream>>>(xb, AxT, part_xa, 8192, 2048, 32, 2);
  k_fin<<<2048, 256, 0, stream>>>(part_xa, xag, xau, 8192, 64, 16);

  // fused gate+up: h = silu(x@Wg^T + lora_g) * (x@Wu^T + lora_u) -> gbuf
  k_gemmGU<<<64 * 43, 256, 0, stream>>>(xb, Wgb, Wub, xag, xau, BgT, BuT,
                                        gbuf, 5504, 2048);

  // ha: [8192 x 32] = h @ AdT^T, split-K 16 chunks (K=5504)
  k_skinny<32><<<64 * 16, 256, 0, stream>>>(gbuf, AdT, part_ha, 8192, 5504, 86, 6);
  k_fin<<<1024, 256, 0, stream>>>(part_ha, ha, ha, 8192, 32, 16);

  // down: out = h@Wd^T + lora (fp32), dual-m-tile blocks
  k_gemmD<<<32 * 16, 256, 0, stream>>>(gbuf, Wdb, ha, BdT, out, 2048, 5504);
}

// Round 7
// 791.806 us; speedup vs baseline: 1.0125x; 1.0125x over previous
//
#include <hip/hip_runtime.h>
#include <stdint.h>

typedef unsigned short u16;
typedef __bf16 bf16x8 __attribute__((ext_vector_type(8)));
typedef float f32x4 __attribute__((ext_vector_type(4)));

#define AS1 __attribute__((address_space(1)))
#define AS3 __attribute__((address_space(3)))

__device__ __forceinline__ void g2l16(const void* g, void* l) {
  __builtin_amdgcn_global_load_lds((AS1 void*)(void*)g, (AS3 void*)l, 16, 0, 0);
}

__device__ __forceinline__ u16 f2bf(float f) {
  union { float f; uint32_t u; } v; v.f = f;
  return (u16)((v.u + 0x7fffu + ((v.u >> 16) & 1u)) >> 16);
}
__device__ __forceinline__ float bf2f(u16 b) {
  union { uint32_t u; float f; } v; v.u = ((uint32_t)b) << 16;
  return v.f;
}

// ---- merged prologue: fp32->bf16 casts (x,Wg,Wu,Wd) + top2 + LoRA panels ----
// blocks [0, 49408): cast region, 12648448 float4s
// blocks [49408, 60736): prep region, 2899968 threads:
//   AxT 524288 | AdT 704512 | BgT 704512 | BuT 704512 | BdT 262144
__global__ void k_pre(const float* __restrict__ x, u16* __restrict__ xb,
                      const float* __restrict__ Wg, u16* __restrict__ Wgb,
                      const float* __restrict__ Wu, u16* __restrict__ Wub,
                      const float* __restrict__ Wd, u16* __restrict__ Wdb,
                      const float* __restrict__ gv,
                      const float* __restrict__ Ag, const float* __restrict__ Au,
                      const float* __restrict__ Ad,
                      const float* __restrict__ Bg, const float* __restrict__ Bu,
                      const float* __restrict__ Bd,
                      u16* __restrict__ AxT, u16* __restrict__ AdT,
                      u16* __restrict__ BgT, u16* __restrict__ BuT,
                      u16* __restrict__ BdT) {
  __shared__ int sidx[8];
  if (blockIdx.x < 49408) {
    int i = blockIdx.x * 256 + threadIdx.x;
    const float* in; u16* out; int j;
    if (i < 4194304) { in = x; out = xb; j = i; }
    else if (i < 4194304 + 2818048) { in = Wg; out = Wgb; j = i - 4194304; }
    else if (i < 4194304 + 2 * 2818048) { in = Wu; out = Wub; j = i - 4194304 - 2818048; }
    else { in = Wd; out = Wdb; j = i - 4194304 - 2 * 2818048; }
    float4 v = ((const float4*)in)[j];
    ushort4 o = make_ushort4(f2bf(v.x), f2bf(v.y), f2bf(v.z), f2bf(v.w));
    ((ushort4*)out)[j] = o;
    return;
  }
  if (threadIdx.x == 0) {
    #pragma unroll
    for (int b = 0; b < 4; ++b) {
      const float* g = gv + b * 8;
      int i1 = 0; float v1 = g[0];
      for (int e = 1; e < 8; ++e) if (g[e] > v1) { v1 = g[e]; i1 = e; }
      int i2 = -1; float v2 = -3.0e38f;
      for (int e = 0; e < 8; ++e) if (e != i1 && g[e] > v2) { v2 = g[e]; i2 = e; }
      sidx[2 * b] = i1; sidx[2 * b + 1] = i2;
    }
  }
  __syncthreads();
  int t = (blockIdx.x - 49408) * 256 + threadIdx.x;
  if (t < 524288) {  // AxT: Kd=2048, jmax=64 (gate|up stacked)
    int h = t % 2048;
    int j = (t / 2048) & 63;
    int b = t / (2048 * 64);
    const float* src = (j >= 32) ? Au : Ag;
    int jj = j & 31;
    int e = sidx[2 * b + ((jj >> 4) & 1)];
    AxT[t] = f2bf(src[((size_t)e * 2048 + h) * 16 + (jj & 15)]);
    return;
  }
  t -= 524288;
  if (t < 704512) {  // AdT: Kd=5504, jmax=32
    int h = t % 5504;
    int j = (t / 5504) & 31;
    int b = t / (5504 * 32);
    int e = sidx[2 * b + ((j >> 4) & 1)];
    AdT[t] = f2bf(Ad[((size_t)e * 5504 + h) * 16 + (j & 15)]);
    return;
  }
  t -= 704512;
  if (t < 704512) {  // BgT: N=5504
    int j = t & 31;
    int n = (t >> 5) % 5504;
    int b = t / (5504 * 32);
    int e = (j & 16) ? sidx[2 * b + 1] : sidx[2 * b];
    BgT[t] = f2bf(Bg[((size_t)e * 16 + (j & 15)) * 5504 + n]);
    return;
  }
  t -= 704512;
  if (t < 704512) {  // BuT: N=5504
    int j = t & 31;
    int n = (t >> 5) % 5504;
    int b = t / (5504 * 32);
    int e = (j & 16) ? sidx[2 * b + 1] : sidx[2 * b];
    BuT[t] = f2bf(Bu[((size_t)e * 16 + (j & 15)) * 5504 + n]);
    return;
  }
  t -= 704512;
  if (t < 262144) {  // BdT: N=2048
    int j = t & 31;
    int n = (t >> 5) % 2048;
    int b = t / (2048 * 32);
    int e = (j & 16) ? sidx[2 * b + 1] : sidx[2 * b];
    BdT[t] = f2bf(Bd[((size_t)e * 16 + (j & 15)) * 2048 + n]);
  }
}

// ---- skinny MFMA GEMM with split-K (xa = xb @ AxT^T) ----
template <int N2>
__global__ __launch_bounds__(256) void k_skinny(
    const u16* __restrict__ A, const u16* __restrict__ BT,
    float* __restrict__ part, int M, int K, int total_iters, int iters_per_chunk) {
  __shared__ u16 sA[128 * 64];
  __shared__ u16 sB[N2 * 64];
  int nm = M >> 7;
  int bm = blockIdx.x % nm, chunk = blockIdx.x / nm;
  int m0 = bm << 7;
  int batch = m0 >> 11;
  int tid = threadIdx.x, lane = tid & 63, w = tid >> 6;
  int kb = chunk * iters_per_chunk;
  int ke = min(total_iters, kb + iters_per_chunk);

  const u16* Bb = BT + (size_t)batch * N2 * K;

  const u16* ga[4]; u16* la[4];
  #pragma unroll
  for (int t = 0; t < 4; ++t) {
    int cb = 4 * w + t;
    int q = cb * 64 + lane;
    int row = q >> 3;
    int c = (q & 7) ^ (row & 7);
    ga[t] = A + (size_t)(m0 + row) * K + (size_t)kb * 64 + c * 8;
    la[t] = sA + cb * 512;
  }
  constexpr int nB = N2 / 32;
  const u16* gb[nB]; u16* lb[nB];
  #pragma unroll
  for (int t = 0; t < nB; ++t) {
    int cb = nB * w + t;
    int q = cb * 64 + lane;
    int row = q >> 3;
    int c = (q & 7) ^ (row & 7);
    gb[t] = Bb + (size_t)row * K + (size_t)kb * 64 + c * 8;
    lb[t] = sB + cb * 512;
  }

  f32x4 acc[2][N2 / 16] = {};
  for (int kt = kb; kt < ke; ++kt) {
    #pragma unroll
    for (int t = 0; t < 4; ++t) { g2l16(ga[t], la[t]); ga[t] += 64; }
    #pragma unroll
    for (int t = 0; t < nB; ++t) { g2l16(gb[t], lb[t]); gb[t] += 64; }
    __syncthreads();
    #pragma unroll
    for (int ks = 0; ks < 2; ++ks) {
      int cb0 = ks * 4 + (lane >> 4);
      bf16x8 af[2], bfr[N2 / 16];
      #pragma unroll
      for (int mi = 0; mi < 2; ++mi) {
        int row = 32 * w + mi * 16 + (lane & 15);
        af[mi] = *(const bf16x8*)(sA + (row * 8 + (cb0 ^ (row & 7))) * 8);
      }
      #pragma unroll
      for (int ni = 0; ni < N2 / 16; ++ni) {
        int row = ni * 16 + (lane & 15);
        bfr[ni] = *(const bf16x8*)(sB + (row * 8 + (cb0 ^ (row & 7))) * 8);
      }
      #pragma unroll
      for (int mi = 0; mi < 2; ++mi)
        #pragma unroll
        for (int ni = 0; ni < N2 / 16; ++ni)
          acc[mi][ni] = __builtin_amdgcn_mfma_f32_16x16x32_bf16(
              af[mi], bfr[ni], acc[mi][ni], 0, 0, 0);
    }
    __syncthreads();
  }

  int rb = (lane >> 4) * 4, cc = lane & 15;
  #pragma unroll
  for (int mi = 0; mi < 2; ++mi)
    #pragma unroll
    for (int ni = 0; ni < N2 / 16; ++ni)
      #pragma unroll
      for (int reg = 0; reg < 4; ++reg) {
        int gr = m0 + 32 * w + mi * 16 + rb + reg;
        int gc = ni * 16 + cc;
        part[((size_t)chunk * M + gr) * N2 + gc] = acc[mi][ni][reg];
      }
}

// ---- finalize split-K: out = bf16(2 * sum_chunks part) ----
__global__ void k_fin(const float* __restrict__ part, u16* __restrict__ out0,
                      u16* __restrict__ out1, int M, int N2, int nch) {
  int t = blockIdx.x * 256 + threadIdx.x;
  if (t >= M * N2) return;
  float s = 0.f;
  for (int c = 0; c < nch; ++c) s += part[(size_t)c * M * N2 + t];
  int j = t % N2, bs = t / N2;
  u16 v = f2bf(2.0f * s);
  if (N2 == 64) {
    if (j < 32) out0[(size_t)bs * 32 + j] = v;
    else        out1[(size_t)bs * 32 + (j - 32)] = v;
  } else {
    out0[(size_t)bs * 32 + j] = v;
  }
}

// ================= fused gate+up GEMM (+ non-atomic ha fold) =================
// One block computes both gate and up 128x128 tiles (A staged once); epilogue
// h = silu(g)*u -> gbuf AND swizzled LDS; then waves 0-1 compute this block's
// n-slice contribution to ha = h @ AdT^T (full local K-sum over both 64-col
// halves) and store to a PRIVATE split-K slot part[bn] -- plain coalesced
// stores, no atomics (R5's atomic variant doubled WRITE_SIZE; this adds only
// 45 MB). k_fin(nch=43) reduces the slots.
__global__ __launch_bounds__(256, 2)
void k_gemmGU(const u16* __restrict__ A, const u16* __restrict__ Bg_,
              const u16* __restrict__ Bu_,
              const u16* __restrict__ A2g, const u16* __restrict__ A2u,
              const u16* __restrict__ B2g, const u16* __restrict__ B2u,
              const u16* __restrict__ AdT, float* __restrict__ part,
              u16* __restrict__ Out, int N, int K) {
  __shared__ u16 sA[128 * 64];
  __shared__ u16 sG[128 * 64];
  __shared__ u16 sU[128 * 64];
  int nt = N >> 7;
  int nm = gridDim.x / nt;
  int perx = nm >> 3;
  int xcd = blockIdx.x & 7;
  int v = blockIdx.x >> 3;
  int bn = v / perx;
  int bm = xcd * perx + (v - bn * perx);
  int m0 = bm << 7, n0 = bn << 7;
  int batch = m0 >> 11;
  int tid = threadIdx.x, lane = tid & 63, w = tid >> 6;
  int mo = (w & 1) << 6, no = (w >> 1) << 6;

  const u16* ga[4]; const u16* gg[4]; const u16* gu[4];
  u16* la[4]; u16* lg[4]; u16* lu[4];
  #pragma unroll
  for (int t = 0; t < 4; ++t) {
    int cb = 4 * w + t;
    int q = cb * 64 + lane;
    int row = q >> 3;
    int c = (q & 7) ^ (row & 7);
    ga[t] = A + (size_t)(m0 + row) * K + c * 8;
    gg[t] = Bg_ + (size_t)(n0 + row) * K + c * 8;
    gu[t] = Bu_ + (size_t)(n0 + row) * K + c * 8;
    la[t] = sA + cb * 512;
    lg[t] = sG + cb * 512;
    lu[t] = sU + cb * 512;
  }

  f32x4 accg[4][4] = {};
  f32x4 accu[4][4] = {};

  int kiters = K >> 6;
  for (int kt = 0; kt < kiters; ++kt) {
    #pragma unroll
    for (int t = 0; t < 4; ++t) { g2l16(ga[t], la[t]); ga[t] += 64; }
    #pragma unroll
    for (int t = 0; t < 4; ++t) { g2l16(gg[t], lg[t]); gg[t] += 64; }
    #pragma unroll
    for (int t = 0; t < 4; ++t) { g2l16(gu[t], lu[t]); gu[t] += 64; }
    __syncthreads();
    #pragma unroll
    for (int ks = 0; ks < 2; ++ks) {
      bf16x8 af[4], bgf[4], buf_[4];
      int cb0 = ks * 4 + (lane >> 4);
      #pragma unroll
      for (int mi = 0; mi < 4; ++mi) {
        int row = mo + mi * 16 + (lane & 15);
        af[mi] = *(const bf16x8*)(sA + (row * 8 + (cb0 ^ (row & 7))) * 8);
      }
      #pragma unroll
      for (int ni = 0; ni < 4; ++ni) {
        int row = no + ni * 16 + (lane & 15);
        bgf[ni] = *(const bf16x8*)(sG + (row * 8 + (cb0 ^ (row & 7))) * 8);
        buf_[ni] = *(const bf16x8*)(sU + (row * 8 + (cb0 ^ (row & 7))) * 8);
      }
      #pragma unroll
      for (int mi = 0; mi < 4; ++mi)
        #pragma unroll
        for (int ni = 0; ni < 4; ++ni) {
          accg[mi][ni] = __builtin_amdgcn_mfma_f32_16x16x32_bf16(
              af[mi], bgf[ni], accg[mi][ni], 0, 0, 0);
          accu[mi][ni] = __builtin_amdgcn_mfma_f32_16x16x32_bf16(
              af[mi], buf_[ni], accu[mi][ni], 0, 0, 0);
        }
    }
    __syncthreads();
  }

  // LoRA extra K=32 step: gate uses (A2g,B2g), up uses (A2u,B2u)
  {
    const u16* B2gb = B2g + (size_t)batch * N * 32;
    const u16* B2ub = B2u + (size_t)batch * N * 32;
    #pragma unroll
    for (int t = 0; t < 2; ++t) {
      int cb = 2 * w + t;
      int q = cb * 64 + lane;
      int row = q >> 2;
      int c = (q & 3) ^ (row & 3);
      g2l16(A2g + (size_t)(m0 + row) * 32 + c * 8, sA + cb * 512);
      g2l16(A2u + (size_t)(m0 + row) * 32 + c * 8, sA + 4096 + cb * 512);
      g2l16(B2gb + (size_t)(n0 + row) * 32 + c * 8, sG + cb * 512);
      g2l16(B2ub + (size_t)(n0 + row) * 32 + c * 8, sU + cb * 512);
    }
    __syncthreads();
    int c0 = lane >> 4;
    bf16x8 ag2[4], au2[4], bg2[4], bu2[4];
    #pragma unroll
    for (int mi = 0; mi < 4; ++mi) {
      int row = mo + mi * 16 + (lane & 15);
      ag2[mi] = *(const bf16x8*)(sA + (row * 4 + (c0 ^ (row & 3))) * 8);
      au2[mi] = *(const bf16x8*)(sA + 4096 + (row * 4 + (c0 ^ (row & 3))) * 8);
    }
    #pragma unroll
    for (int ni = 0; ni < 4; ++ni) {
      int row = no + ni * 16 + (lane & 15);
      bg2[ni] = *(const bf16x8*)(sG + (row * 4 + (c0 ^ (row & 3))) * 8);
      bu2[ni] = *(const bf16x8*)(sU + (row * 4 + (c0 ^ (row & 3))) * 8);
    }
    #pragma unroll
    for (int mi = 0; mi < 4; ++mi)
      #pragma unroll
      for (int ni = 0; ni < 4; ++ni) {
        accg[mi][ni] = __builtin_amdgcn_mfma_f32_16x16x32_bf16(
            ag2[mi], bg2[ni], accg[mi][ni], 0, 0, 0);
        accu[mi][ni] = __builtin_amdgcn_mfma_f32_16x16x32_bf16(
            au2[mi], bu2[ni], accu[mi][ni], 0, 0, 0);
      }
  }

  __syncthreads();  // all LoRA LDS reads complete before overwriting sA/sG/sU

  // stage AdT[0..32)[n0 .. n0+128) into sA as two 64-col swizzled halves
  {
    const u16* AdTb = AdT + (size_t)batch * 32 * 5504;
    int q = w * 64 + lane;
    int row = q >> 3;
    int c = (q & 7) ^ (row & 7);
    #pragma unroll
    for (int half = 0; half < 2; ++half)
      g2l16(AdTb + (size_t)row * 5504 + n0 + half * 64 + c * 8,
            sA + half * 2048 + w * 512);
  }

  // epilogue: h = silu(g)*u -> global AND swizzled LDS (sG half0, sU half1)
  int rb = (lane >> 4) * 4;
  int cc = lane & 15;
  #pragma unroll
  for (int mi = 0; mi < 4; ++mi) {
    #pragma unroll
    for (int ni = 0; ni < 4; ++ni) {
      #pragma unroll
      for (int reg = 0; reg < 4; ++reg) {
        int gr = m0 + mo + mi * 16 + rb + reg;
        int gc = n0 + no + ni * 16 + cc;
        size_t pos = (size_t)gr * N + gc;
        float gvv = accg[mi][ni][reg];
        float uvv = accu[mi][ni][reg];
        gvv = gvv / (1.f + __expf(-gvv));
        u16 hv = f2bf(gvv * uvv);
        Out[pos] = hv;
        int cl = no + ni * 16 + cc;         // 0..127 block-local col
        u16* sH = (cl < 64) ? sG : sU;
        int c2 = cl & 63;
        int r2 = mo + mi * 16 + rb + reg;   // 0..127 block-local row
        sH[(r2 * 8 + ((c2 >> 3) ^ (r2 & 7))) * 8 + (c2 & 7)] = hv;
      }
    }
  }
  __syncthreads();  // drains AdT g2l16 + h ds_writes

  // mini-GEMM on waves 0,1: rows moh..moh+64, FULL K-sum over both halves;
  // private split-K slot per n-block => plain stores, no atomics.
  if (w < 2) {
    int moh = w << 6;
    f32x4 ah[4][2] = {};
    #pragma unroll
    for (int half = 0; half < 2; ++half) {
      const u16* sH = half ? sU : sG;
      const u16* sAd = sA + half * 2048;
      #pragma unroll
      for (int ks = 0; ks < 2; ++ks) {
        int cb0 = ks * 4 + (lane >> 4);
        bf16x8 afh[4], bfh[2];
        #pragma unroll
        for (int mi = 0; mi < 4; ++mi) {
          int row = moh + mi * 16 + (lane & 15);
          afh[mi] = *(const bf16x8*)(sH + (row * 8 + (cb0 ^ (row & 7))) * 8);
        }
        #pragma unroll
        for (int jf = 0; jf < 2; ++jf) {
          int row = jf * 16 + (lane & 15);
          bfh[jf] = *(const bf16x8*)(sAd + (row * 8 + (cb0 ^ (row & 7))) * 8);
        }
        #pragma unroll
        for (int mi = 0; mi < 4; ++mi)
          #pragma unroll
          for (int jf = 0; jf < 2; ++jf)
            ah[mi][jf] = __builtin_amdgcn_mfma_f32_16x16x32_bf16(
                afh[mi], bfh[jf], ah[mi][jf], 0, 0, 0);
      }
    }
    float* pslot = part + (size_t)bn * 8192 * 32;
    #pragma unroll
    for (int mi = 0; mi < 4; ++mi)
      #pragma unroll
      for (int jf = 0; jf < 2; ++jf)
        #pragma unroll
        for (int reg = 0; reg < 4; ++reg)
          pslot[(size_t)(m0 + moh + mi * 16 + rb + reg) * 32 + jf * 16 + cc] =
              ah[mi][jf][reg];
  }
}

// ================= dual-m-tile down GEMM =================
// One block computes out tiles (m0, n0) and (m0+128, n0): Wd-tile staged ONCE,
// 32 MFMA per wave per K-step.
__global__ __launch_bounds__(256, 2)
void k_gemmD(const u16* __restrict__ A, const u16* __restrict__ Bm,
             const u16* __restrict__ A2, const u16* __restrict__ B2,
             float* __restrict__ Out, int N, int K) {
  __shared__ u16 sA0[128 * 64];
  __shared__ u16 sA1[128 * 64];
  __shared__ u16 sB[128 * 64];
  int nt = N >> 7;                  // 16
  int nm = gridDim.x / nt;          // 32 m-pairs
  int perx = nm >> 3;
  int xcd = blockIdx.x & 7;
  int v = blockIdx.x >> 3;
  int bn = v / perx;
  int bm = xcd * perx + (v - bn * perx);
  int m0 = bm << 8, n0 = bn << 7;
  int batch = m0 >> 11;             // 256-block never straddles a batch
  int tid = threadIdx.x, lane = tid & 63, w = tid >> 6;
  int mo = (w & 1) << 6, no = (w >> 1) << 6;

  const u16* ga0[4]; const u16* ga1[4]; const u16* gb[4];
  u16* la0[4]; u16* la1[4]; u16* lb[4];
  #pragma unroll
  for (int t = 0; t < 4; ++t) {
    int cb = 4 * w + t;
    int q = cb * 64 + lane;
    int row = q >> 3;
    int c = (q & 7) ^ (row & 7);
    ga0[t] = A + (size_t)(m0 + row) * K + c * 8;
    ga1[t] = A + (size_t)(m0 + 128 + row) * K + c * 8;
    gb[t]  = Bm + (size_t)(n0 + row) * K + c * 8;
    la0[t] = sA0 + cb * 512;
    la1[t] = sA1 + cb * 512;
    lb[t]  = sB + cb * 512;
  }

  f32x4 acc0[4][4] = {};
  f32x4 acc1[4][4] = {};

  int kiters = K >> 6;
  for (int kt = 0; kt < kiters; ++kt) {
    #pragma unroll
    for (int t = 0; t < 4; ++t) { g2l16(ga0[t], la0[t]); ga0[t] += 64; }
    #pragma unroll
    for (int t = 0; t < 4; ++t) { g2l16(ga1[t], la1[t]); ga1[t] += 64; }
    #pragma unroll
    for (int t = 0; t < 4; ++t) { g2l16(gb[t], lb[t]); gb[t] += 64; }
    __syncthreads();
    #pragma unroll
    for (int ks = 0; ks < 2; ++ks) {
      bf16x8 af0[4], af1[4], bfr[4];
      int cb0 = ks * 4 + (lane >> 4);
      #pragma unroll
      for (int mi = 0; mi < 4; ++mi) {
        int row = mo + mi * 16 + (lane & 15);
        af0[mi] = *(const bf16x8*)(sA0 + (row * 8 + (cb0 ^ (row & 7))) * 8);
        af1[mi] = *(const bf16x8*)(sA1 + (row * 8 + (cb0 ^ (row & 7))) * 8);
      }
      #pragma unroll
      for (int ni = 0; ni < 4; ++ni) {
        int row = no + ni * 16 + (lane & 15);
        bfr[ni] = *(const bf16x8*)(sB + (row * 8 + (cb0 ^ (row & 7))) * 8);
      }
      #pragma unroll
      for (int mi = 0; mi < 4; ++mi)
        #pragma unroll
        for (int ni = 0; ni < 4; ++ni) {
          acc0[mi][ni] = __builtin_amdgcn_mfma_f32_16x16x32_bf16(
              af0[mi], bfr[ni], acc0[mi][ni], 0, 0, 0);
          acc1[mi][ni] = __builtin_amdgcn_mfma_f32_16x16x32_bf16(
              af1[mi], bfr[ni], acc1[mi][ni], 0, 0, 0);
        }
    }
    __syncthreads();
  }

  // LoRA extra K=32 step: ha tiles at m0 and m0+128, BdT shared
  {
    const u16* B2b = B2 + (size_t)batch * N * 32;
    #pragma unroll
    for (int t = 0; t < 2; ++t) {
      int cb = 2 * w + t;
      int q = cb * 64 + lane;
      int row = q >> 2;
      int c = (q & 3) ^ (row & 3);
      g2l16(A2 + (size_t)(m0 + row) * 32 + c * 8, sA0 + cb * 512);
      g2l16(A2 + (size_t)(m0 + 128 + row) * 32 + c * 8, sA1 + cb * 512);
      g2l16(B2b + (size_t)(n0 + row) * 32 + c * 8, sB + cb * 512);
    }
    __syncthreads();
    int c0 = lane >> 4;
    bf16x8 af0[4], af1[4], bfr[4];
    #pragma unroll
    for (int mi = 0; mi < 4; ++mi) {
      int row = mo + mi * 16 + (lane & 15);
      af0[mi] = *(const bf16x8*)(sA0 + (row * 4 + (c0 ^ (row & 3))) * 8);
      af1[mi] = *(const bf16x8*)(sA1 + (row * 4 + (c0 ^ (row & 3))) * 8);
    }
    #pragma unroll
    for (int ni = 0; ni < 4; ++ni) {
      int row = no + ni * 16 + (lane & 15);
      bfr[ni] = *(const bf16x8*)(sB + (row * 4 + (c0 ^ (row & 3))) * 8);
    }
    #pragma unroll
    for (int mi = 0; mi < 4; ++mi)
      #pragma unroll
      for (int ni = 0; ni < 4; ++ni) {
        acc0[mi][ni] = __builtin_amdgcn_mfma_f32_16x16x32_bf16(
            af0[mi], bfr[ni], acc0[mi][ni], 0, 0, 0);
        acc1[mi][ni] = __builtin_amdgcn_mfma_f32_16x16x32_bf16(
            af1[mi], bfr[ni], acc1[mi][ni], 0, 0, 0);
      }
  }

  int rb = (lane >> 4) * 4;
  int cc = lane & 15;
  #pragma unroll
  for (int mi = 0; mi < 4; ++mi) {
    #pragma unroll
    for (int ni = 0; ni < 4; ++ni) {
      #pragma unroll
      for (int reg = 0; reg < 4; ++reg) {
        int gr = m0 + mo + mi * 16 + rb + reg;
        int gc = n0 + no + ni * 16 + cc;
        Out[(size_t)gr * N + gc] = acc0[mi][ni][reg];
        Out[(size_t)(gr + 128) * N + gc] = acc1[mi][ni][reg];
      }
    }
  }
}

extern "C" void kernel_launch(void* const* d_in, const int* in_sizes, int n_in,
                              void* d_out, int out_size, void* d_ws, size_t ws_size,
                              hipStream_t stream) {
  const float* x  = (const float*)d_in[0];
  const float* gv = (const float*)d_in[1];
  const float* Wg = (const float*)d_in[2];
  const float* Ag = (const float*)d_in[3];
  const float* Bg = (const float*)d_in[4];
  const float* Wu = (const float*)d_in[5];
  const float* Au = (const float*)d_in[6];
  const float* Bu = (const float*)d_in[7];
  const float* Wd = (const float*)d_in[8];
  const float* Ad = (const float*)d_in[9];
  const float* Bd = (const float*)d_in[10];
  float* out = (float*)d_out;

  char* ws = (char*)d_ws;
  size_t off = 0;
  auto alloc = [&](size_t bytes) -> void* {
    void* p = ws + off;
    off = (off + bytes + 255) & ~(size_t)255;
    return p;
  };
  u16* xb   = (u16*)alloc((size_t)8192 * 2048 * 2);
  u16* Wgb  = (u16*)alloc((size_t)5504 * 2048 * 2);
  u16* Wub  = (u16*)alloc((size_t)5504 * 2048 * 2);
  u16* Wdb  = (u16*)alloc((size_t)2048 * 5504 * 2);
  u16* xag  = (u16*)alloc((size_t)8192 * 32 * 2);
  u16* xau  = (u16*)alloc((size_t)8192 * 32 * 2);
  u16* ha   = (u16*)alloc((size_t)8192 * 32 * 2);
  u16* BgT  = (u16*)alloc((size_t)4 * 5504 * 32 * 2);
  u16* BuT  = (u16*)alloc((size_t)4 * 5504 * 32 * 2);
  u16* BdT  = (u16*)alloc((size_t)4 * 2048 * 32 * 2);
  u16* AxT  = (u16*)alloc((size_t)4 * 64 * 2048 * 2);
  u16* AdT  = (u16*)alloc((size_t)4 * 32 * 5504 * 2);
  float* part_had = (float*)alloc((size_t)43 * 8192 * 32 * 4);  // 45 MB
  u16* gbuf = (u16*)alloc((size_t)8192 * 5504 * 2);
  if (off > ws_size) return;

  // split-K partial buffer for xa lives in gbuf (dead until GU)
  float* part_xa = (float*)gbuf;   // 16*8192*64*4 = 33.5MB <= 90MB

  // merged casts + LoRA prep: 49408 cast blocks + 11328 prep blocks
  k_pre<<<60736, 256, 0, stream>>>(x, xb, Wg, Wgb, Wu, Wub, Wd, Wdb,
                                   gv, Ag, Au, Ad, Bg, Bu, Bd,
                                   AxT, AdT, BgT, BuT, BdT);

  // xa: [8192 x 64] = xb @ AxT^T, split-K 16 chunks (K=2048)
  k_skinny<64><<<64 * 16, 256, 0, stream>>>(xb, AxT, part_xa, 8192, 2048, 32, 2);
  k_fin<<<2048, 256, 0, stream>>>(part_xa, xag, xau, 8192, 64, 16);

  // fused gate+up (+ non-atomic ha fold): h -> gbuf, ha partials -> part_had
  k_gemmGU<<<64 * 43, 256, 0, stream>>>(xb, Wgb, Wub, xag, xau, BgT, BuT,
                                        AdT, part_had, gbuf, 5504, 2048);

  // ha = bf16(2 * sum over 43 n-block slots)
  k_fin<<<1024, 256, 0, stream>>>(part_had, ha, ha, 8192, 32, 43);

  // down: out = h@Wd^T + lora (fp32), dual-m-tile blocks
  k_gemmD<<<32 * 16, 256, 0, stream>>>(gbuf, Wdb, ha, BdT, out, 2048, 5504);
}